// Round 1
// baseline (673.132 us; speedup 1.0000x reference)
//
#include <hip/hip_runtime.h>
#include <math.h>

typedef unsigned short u16;
typedef unsigned int u32;
typedef __attribute__((ext_vector_type(2))) u32 u32x2;
typedef __attribute__((ext_vector_type(8))) short short8;
typedef __attribute__((ext_vector_type(4))) float f32x4;
typedef __attribute__((ext_vector_type(2))) float f32x2;

// ---------------- workspace layout (bytes) ----------------
// planes_t: 3*512*512 texels * 40 bf16 ch (c>=36 zero)   = 62,914,560
// lines_t : 3*512 texels * 40 bf16                        =    122,880
// w1s     : 16 nt * 5 kt * 64 lanes * 8 bf16              =     81,920
// w2s     : 12 nt * 8 kt * 64 lanes * 8 bf16              =     98,304
#define OFF_LINES_T 62914560u
#define OFF_W1S     63037440u
#define OFF_W2S     63119360u
#define WS_NEEDED   63217664u

__device__ __forceinline__ float bf_lo(u32 u){ union{u32 i;float f;} v; v.i = u << 16; return v.f; }
__device__ __forceinline__ float bf_hi(u32 u){ union{u32 i;float f;} v; v.i = u & 0xffff0000u; return v.f; }
// RTNE pack (precompute kernels only — cost irrelevant there)
__device__ __forceinline__ u16 f2bf(float f){ union{float f;u32 i;} v; v.f=f; u32 i=v.i; return (u16)((i + 0x7fffu + ((i>>16)&1u)) >> 16); }
__device__ __forceinline__ u32 pack2bf(float lo, float hi){ return (u32)f2bf(lo) | ((u32)f2bf(hi)<<16); }
// fast round-half-up pack: 2 adds + v_perm (vs ~9 inst RTNE); error <= 0.5 ulp
__device__ __forceinline__ u32 pack2bf_fast(float lo, float hi){
  return __builtin_amdgcn_perm(__float_as_uint(hi) + 0x8000u,
                               __float_as_uint(lo) + 0x8000u, 0x07060302u);
}
__device__ __forceinline__ u16 f2bf_fast(float f){ return (u16)((__float_as_uint(f) + 0x8000u) >> 16); }

// LDS k'-layout (160 slots): [0..35]=mode0, [36..39]=0, [40..75]=mode1, [76..79]=0,
// [80..115]=mode2, [116..119]=0, [120..140]=PE(21), [141..159]=0.
__device__ __forceinline__ int map_k1(int kp){
  if (kp < 120){ int g = kp/40, r = kp - g*40; return (r<36) ? g*36 + r : -1; }
  if (kp < 141) return kp - 12;   // 108 + (kp-120)
  return -1;
}

// ---------------- fused precompute: all 4 transposes in ONE launch ----------------
// blocks [0,3072)    : plane transpose (C,H,W) f32 -> (H,W,C40) bf16
// blocks [3072,3078) : line transpose (C,L) f32 -> (L,C40) bf16
// blocks [3078,3098) : W1 (129x256 f32) -> bf16 B-frags, K remapped/padded to 160
// blocks [3098,3122) : W2 (256x129 f32) -> bf16 B-frags, N padded to 192
#define NB_TP 3072
#define NB_TL 6
#define NB_W1 20
#define NB_W2 24
__global__ void k_pre(const float* __restrict__ planes, const float* __restrict__ lines,
                      const float* __restrict__ W1, const float* __restrict__ W2,
                      u16* __restrict__ pt, u16* __restrict__ lt,
                      u16* __restrict__ w1s, u16* __restrict__ w2s){
  const int b = blockIdx.x;
  const int tid = threadIdx.x;
  if (b < NB_TP){
    int t = b*256 + tid;                         // 0 .. 786431  (3*512*512)
    int i = t >> 18;
    int yx = t & 262143;
    const float* src = planes + (size_t)i*9437184 + yx;   // i*36*262144 + y*512 + x
    uint4* dst = reinterpret_cast<uint4*>(pt + (size_t)t*40);
#pragma unroll
    for (int cc=0; cc<5; cc++){
      float v[8];
#pragma unroll
      for (int e=0;e<8;e++){
        int c = cc*8+e;
        v[e] = (c<36) ? src[(size_t)c*262144] : 0.f;
      }
      uint4 o; o.x=pack2bf(v[0],v[1]); o.y=pack2bf(v[2],v[3]); o.z=pack2bf(v[4],v[5]); o.w=pack2bf(v[6],v[7]);
      dst[cc]=o;
    }
  } else if (b < NB_TP+NB_TL){
    int t = (b-NB_TP)*256 + tid;                 // 0 .. 1535 (3*512)
    int i = t >> 9, g = t & 511;
    const float* src = lines + (size_t)i*18432 + g;       // i*36*512 + g
    uint4* dst = reinterpret_cast<uint4*>(lt + (size_t)t*40);
#pragma unroll
    for (int cc=0; cc<5; cc++){
      float v[8];
#pragma unroll
      for (int e=0;e<8;e++){
        int c = cc*8+e;
        v[e] = (c<36) ? src[(size_t)c*512] : 0.f;
      }
      uint4 o; o.x=pack2bf(v[0],v[1]); o.y=pack2bf(v[2],v[3]); o.z=pack2bf(v[4],v[5]); o.w=pack2bf(v[6],v[7]);
      dst[cc]=o;
    }
  } else if (b < NB_TP+NB_TL+NB_W1){
    int t = (b-(NB_TP+NB_TL))*256 + tid;         // 0..5119 = 80 frags * 64 lanes
    int lane = t & 63;
    int fid = t >> 6;                            // nt*5 + kt
    int nt = fid/5, kt = fid - nt*5;
    int n = nt*16 + (lane & 15);
    int kb = kt*32 + (lane >> 4)*8;
    float v[8];
#pragma unroll
    for (int j=0;j<8;j++){ int k = map_k1(kb+j); v[j] = (k>=0) ? W1[k*256+n] : 0.f; }
    uint4 o; o.x=pack2bf(v[0],v[1]); o.y=pack2bf(v[2],v[3]); o.z=pack2bf(v[4],v[5]); o.w=pack2bf(v[6],v[7]);
    *reinterpret_cast<uint4*>(w1s + (size_t)t*8) = o;
  } else {
    int t = (b-(NB_TP+NB_TL+NB_W1))*256 + tid;   // 0..6143 = 96 frags * 64 lanes
    int lane = t & 63;
    int fid = t >> 6;                            // nt*8 + kt
    int kb = (fid & 7)*32 + (lane >> 4)*8;
    int n = (fid >> 3)*16 + (lane & 15);
    float v[8];
#pragma unroll
    for (int j=0;j<8;j++){ int k = kb+j; v[j] = (n<129) ? W2[k*129+n] : 0.f; }
    uint4 o; o.x=pack2bf(v[0],v[1]); o.y=pack2bf(v[2],v[3]); o.z=pack2bf(v[4],v[5]); o.w=pack2bf(v[6],v[7]);
    *reinterpret_cast<uint4*>(w2s + (size_t)t*8) = o;
  }
}

// unpack 2 packed bf16 -> float2 (2 VALU)
__device__ __forceinline__ f32x2 bfx2(u32 u){
  f32x2 r;
  r.x = __uint_as_float(u << 16);
  r.y = __uint_as_float(u & 0xffff0000u);
  return r;
}

// weight-form bilinear*line on 2 packed channels: 7 packed FLOP + 12 unpack + 3 pack
// (vs lerp-form ~33 VALU). float2 ops may emit v_pk_fma_f32 (VOP3P) on gfx950.
__device__ __forceinline__ u32 blend2(u32 u00,u32 u01,u32 u10,u32 u11,u32 g0,u32 g1,
                                      float w00,float w01,float w10,float w11,
                                      float v0,float v1){
  f32x2 pf = bfx2(u00)*w00 + bfx2(u01)*w01 + bfx2(u10)*w10 + bfx2(u11)*w11;
  f32x2 lf = bfx2(g0)*v0 + bfx2(g1)*v1;
  f32x2 r  = pf*lf;
  return pack2bf_fast(r.x, r.y);
}

#define FSTRIDE 168   // feature LDS row stride (u16), 336B: 84 dw -> 2-way bank alias only (free)
#define HSTRIDE 264   // H LDS row stride (u16), 528B: 132 dw -> 2-way alias only (free)

// ---------------- fused gather + MLP ----------------
// 512 threads = 8 waves, 64 points/block. 8 threads/point: q=0..5 gather
// (plane q>>1, 20-slot half q&1), q=6 PE slots 120..139, q=7 PE slot 140 + zeros
// (slots 140..159 MUST be written: uninit LDS NaN x zero-weight still poisons
// the MFMA accumulator). Gather: ALL 30 texel/line loads hoisted to register
// arrays BEFORE blending -> 30-deep MLP per wave (was ~6: per-c round trips to
// L3 at ~400cy each serialized). VGPR rises ~48->~100 (16 waves/CU); the MFMA
// and softplus phases tolerate that; the gather phase gains 2.5x loads in flight.
__global__ void __launch_bounds__(512, 4) k_main(
    const float* __restrict__ xyz, const u16* __restrict__ pt,
    const u16* __restrict__ lt, const u16* __restrict__ w1s,
    const u16* __restrict__ w2s, const float* __restrict__ b1,
    const float* __restrict__ b2, float* __restrict__ out)
{
  __shared__ u16 smem[64*HSTRIDE];   // 33,792 B; feat-tile (stride 168) aliased by H-tile (stride 264)
  const int tid = threadIdx.x;
  const int p = tid >> 3, q = tid & 7;
  const int gp = blockIdx.x*64 + p;
  const float u0 = xyz[gp*3], u1 = xyz[gp*3+1], u2 = xyz[gp*3+2];
  const float xn0 = 2.f*u0-1.f, xn1 = 2.f*u1-1.f, xn2 = 2.f*u2-1.f;

  if (q < 6){
    const int i = q >> 1, part = q & 1;
    // MAT_MODE=[(0,1),(0,2),(1,2)], VEC_MODE=[2,1,0]; x<-m0, y<-m1
    float gxv, gyv, gzv;
    if      (i==0){ gxv=xn0; gyv=xn1; gzv=xn2; }
    else if (i==1){ gxv=xn0; gyv=xn2; gzv=xn1; }
    else          { gxv=xn1; gyv=xn2; gzv=xn0; }
    float px=(gxv+1.0f)*0.5f*511.0f, py=(gyv+1.0f)*0.5f*511.0f, pz=(gzv+1.0f)*0.5f*511.0f;
    float fx=fminf(fmaxf(floorf(px),0.f),510.f);
    float fy=fminf(fmaxf(floorf(py),0.f),510.f);
    float fz=fminf(fmaxf(floorf(pz),0.f),510.f);
    int ix=(int)fx, iy=(int)fy, iz=(int)fz;
    float wx=px-fx, wy=py-fy, wz=pz-fz;
    // precompute bilinear/line weights once (weight-form: 4 fma/ch vs 6 for lerps)
    const float cwx = 1.f-wx, cwy = 1.f-wy;
    const float w00 = cwx*cwy, w01 = wx*cwy, w10 = cwx*wy, w11 = wx*wy;
    const float v0 = 1.f-wz, v1 = wz;
    const u16* base  = pt + (size_t)((i<<18)+(iy<<9)+ix)*40 + part*20;
    const u16* lbase = lt + (size_t)((i<<9)+iz)*40 + part*20;

    // phase 1: issue ALL loads (30 x 8B), fully unrolled -> static reg arrays
    u32x2 A00[5],A01[5],A10[5],A11[5],E0[5],E1[5];
#pragma unroll
    for (int c=0; c<5; c++){
      A00[c] = *reinterpret_cast<const u32x2*>(base + c*4);
      A01[c] = *reinterpret_cast<const u32x2*>(base + 40 + c*4);
      A10[c] = *reinterpret_cast<const u32x2*>(base + 20480 + c*4);
      A11[c] = *reinterpret_cast<const u32x2*>(base + 20520 + c*4);
      E0[c]  = *reinterpret_cast<const u32x2*>(lbase + c*4);
      E1[c]  = *reinterpret_cast<const u32x2*>(lbase + 40 + c*4);
    }
    // phase 2: blend + LDS write
    u16* dst = smem + p*FSTRIDE + i*40 + part*20;
#pragma unroll
    for (int c=0; c<5; c++){
      u32x2 o;
      o.x = blend2(A00[c].x,A01[c].x,A10[c].x,A11[c].x,E0[c].x,E1[c].x, w00,w01,w10,w11,v0,v1);
      o.y = blend2(A00[c].y,A01[c].y,A10[c].y,A11[c].y,E0[c].y,E1[c].y, w00,w01,w10,w11,v0,v1);
      *reinterpret_cast<u32x2*>(dst + c*4) = o;
    }
  } else if (q == 6){
    // PE slots 120..139: [x(3), sin(x), cos(x), sin(2x), cos(2x), sin(4x), cos(4x)[0..1]]
    float v[20];
    v[0]=xn0; v[1]=xn1; v[2]=xn2;
    v[3]=__sinf(xn0);      v[4]=__sinf(xn1);      v[5]=__sinf(xn2);
    v[6]=__cosf(xn0);      v[7]=__cosf(xn1);      v[8]=__cosf(xn2);
    v[9]=__sinf(2.f*xn0);  v[10]=__sinf(2.f*xn1); v[11]=__sinf(2.f*xn2);
    v[12]=__cosf(2.f*xn0); v[13]=__cosf(2.f*xn1); v[14]=__cosf(2.f*xn2);
    v[15]=__sinf(4.f*xn0); v[16]=__sinf(4.f*xn1); v[17]=__sinf(4.f*xn2);
    v[18]=__cosf(4.f*xn0); v[19]=__cosf(4.f*xn1);
    u16* dst = smem + p*FSTRIDE + 120;
#pragma unroll
    for (int c=0; c<10; c++)
      *reinterpret_cast<u32*>(dst + c*2) = pack2bf_fast(v[c*2], v[c*2+1]);
  } else {
    // q==7 (was idle): PE slot 140 = cos(4*xn2), slots 141..159 explicit zeros
    u16* dst = smem + p*FSTRIDE + 140;
    *reinterpret_cast<u32*>(dst) = pack2bf_fast(__cosf(4.f*xn2), 0.f);
#pragma unroll
    for (int c=1; c<10; c++)
      *reinterpret_cast<u32*>(dst + c*2) = 0u;
  }
  __syncthreads();

  // ---- stage 1: H = softplus(100*(feat@W1+b1))/100, M=64 K=160 N=256 ----
  const int lane = tid & 63;
  const int w = tid >> 6;            // 0..7
  const int wm = w & 1, wn = w >> 1; // 2 m-tiles x 4 n-tiles per wave
  const int lm = lane & 15;
  const int quad = lane >> 4;
  const f32x4 zero = {0.f,0.f,0.f,0.f};
  f32x4 acc1[2][4];
#pragma unroll
  for (int mt=0; mt<2; mt++)
#pragma unroll
    for (int nt=0; nt<4; nt++) acc1[mt][nt] = zero;

#pragma unroll
  for (int kt=0; kt<5; kt++){
    short8 a[2];
#pragma unroll
    for (int mt=0; mt<2; mt++)
      a[mt] = *reinterpret_cast<const short8*>(smem + ((wm*2+mt)*16 + lm)*FSTRIDE + kt*32 + quad*8);
    short8 b[4];
#pragma unroll
    for (int nt=0; nt<4; nt++)
      b[nt] = *reinterpret_cast<const short8*>(w1s + (size_t)(((wn*4+nt)*5 + kt)*64 + lane)*8);
#pragma unroll
    for (int mt=0; mt<2; mt++)
#pragma unroll
      for (int nt=0; nt<4; nt++)
        acc1[mt][nt] = __builtin_amdgcn_mfma_f32_16x16x32_bf16(a[mt], b[nt], acc1[mt][nt], 0,0,0);
  }
  __syncthreads();   // all feat reads done before H overwrites the same LDS

#pragma unroll
  for (int nt=0; nt<4; nt++){
    int col = wn*64 + nt*16 + lm;
    float bias = b1[col];
#pragma unroll
    for (int mt=0; mt<2; mt++){
#pragma unroll
      for (int r=0; r<4; r++){
        float xv = acc1[mt][nt][r] + bias;
        float z = 100.f*xv;
        float y = (z > 15.f) ? xv : __logf(1.f + __expf(z))*0.01f;
        int row = (wm*2+mt)*16 + quad*4 + r;
        smem[row*HSTRIDE + col] = f2bf_fast(y);
      }
    }
  }
  __syncthreads();

  // ---- stage 2: out = H@W2 + b2, M=64 K=256 N=144(->192 padded) ----
  f32x4 acc2[2][3];
#pragma unroll
  for (int mt=0; mt<2; mt++)
#pragma unroll
    for (int nt=0; nt<3; nt++) acc2[mt][nt] = zero;

#pragma unroll
  for (int kt=0; kt<8; kt++){
    short8 a[2];
#pragma unroll
    for (int mt=0; mt<2; mt++)
      a[mt] = *reinterpret_cast<const short8*>(smem + ((wm*2+mt)*16 + lm)*HSTRIDE + kt*32 + quad*8);
    short8 b[3];
#pragma unroll
    for (int nt=0; nt<3; nt++){
      int ntg = wn*3 + nt;
      b[nt] = *reinterpret_cast<const short8*>(w2s + (size_t)((ntg*8 + kt)*64 + lane)*8);
    }
#pragma unroll
    for (int mt=0; mt<2; mt++)
#pragma unroll
      for (int nt=0; nt<3; nt++)
        acc2[mt][nt] = __builtin_amdgcn_mfma_f32_16x16x32_bf16(a[mt], b[nt], acc2[mt][nt], 0,0,0);
  }

  // out is 270 MB write-once, never re-read -> non-temporal so it doesn't evict
  // the gather table (pt) from L2 while k_main runs.
#pragma unroll
  for (int nt=0; nt<3; nt++){
    int j = (wn*3 + nt)*16 + lm;
    if (j < 129){
      float bias = b2[j];
#pragma unroll
      for (int mt=0; mt<2; mt++){
#pragma unroll
        for (int r=0; r<4; r++){
          int row = (wm*2+mt)*16 + quad*4 + r;
          __builtin_nontemporal_store(acc2[mt][nt][r] + bias,
                                      &out[(size_t)(blockIdx.x*64 + row)*129 + j]);
        }
      }
    }
  }
}

extern "C" void kernel_launch(void* const* d_in, const int* in_sizes, int n_in,
                              void* d_out, int out_size, void* d_ws, size_t ws_size,
                              hipStream_t stream) {
  const float* xyz    = (const float*)d_in[0];
  const float* planes = (const float*)d_in[1];
  const float* lines  = (const float*)d_in[2];
  const float* W1     = (const float*)d_in[3];
  const float* b1     = (const float*)d_in[4];
  const float* W2     = (const float*)d_in[5];
  const float* b2     = (const float*)d_in[6];
  if (ws_size < (size_t)WS_NEEDED) return;   // workspace too small: fail loudly (validation will show it)

  u16* pt  = (u16*)((char*)d_ws);
  u16* lt  = (u16*)((char*)d_ws + OFF_LINES_T);
  u16* w1s = (u16*)((char*)d_ws + OFF_W1S);
  u16* w2s = (u16*)((char*)d_ws + OFF_W2S);

  k_pre<<<NB_TP+NB_TL+NB_W1+NB_W2, 256, 0, stream>>>(planes, lines, W1, W2, pt, lt, w1s, w2s);
  k_main<<<8192, 512, 0, stream>>>(xyz, pt, lt, w1s, w2s, b1, b2, (float*)d_out);
}

// Round 2
// 646.220 us; speedup vs baseline: 1.0416x; 1.0416x over previous
//
#include <hip/hip_runtime.h>
#include <math.h>

typedef unsigned short u16;
typedef unsigned int u32;
typedef __attribute__((ext_vector_type(2))) u32 u32x2;
typedef __attribute__((ext_vector_type(8))) short short8;
typedef __attribute__((ext_vector_type(4))) float f32x4;
typedef __attribute__((ext_vector_type(2))) float f32x2;

// ---------------- workspace layout (bytes) ----------------
// planes_t: 3*512*512 texels * 40 bf16 ch (c>=36 zero)   = 62,914,560
// lines_t : 3*512 texels * 40 bf16                        =    122,880
// w1s     : 16 nt * 5 kt * 64 lanes * 8 bf16              =     81,920
// w2s     : 12 nt * 8 kt * 64 lanes * 8 bf16              =     98,304
#define OFF_LINES_T 62914560u
#define OFF_W1S     63037440u
#define OFF_W2S     63119360u
#define WS_NEEDED   63217664u

__device__ __forceinline__ float bf_lo(u32 u){ union{u32 i;float f;} v; v.i = u << 16; return v.f; }
__device__ __forceinline__ float bf_hi(u32 u){ union{u32 i;float f;} v; v.i = u & 0xffff0000u; return v.f; }
// RTNE pack (precompute kernels only — cost irrelevant there)
__device__ __forceinline__ u16 f2bf(float f){ union{float f;u32 i;} v; v.f=f; u32 i=v.i; return (u16)((i + 0x7fffu + ((i>>16)&1u)) >> 16); }
__device__ __forceinline__ u32 pack2bf(float lo, float hi){ return (u32)f2bf(lo) | ((u32)f2bf(hi)<<16); }
// fast round-half-up pack: 2 adds + v_perm (vs ~9 inst RTNE); error <= 0.5 ulp
__device__ __forceinline__ u32 pack2bf_fast(float lo, float hi){
  return __builtin_amdgcn_perm(__float_as_uint(hi) + 0x8000u,
                               __float_as_uint(lo) + 0x8000u, 0x07060302u);
}
__device__ __forceinline__ u16 f2bf_fast(float f){ return (u16)((__float_as_uint(f) + 0x8000u) >> 16); }

// LDS k'-layout (160 slots): [0..35]=mode0, [36..39]=0, [40..75]=mode1, [76..79]=0,
// [80..115]=mode2, [116..119]=0, [120..140]=PE(21), [141..159]=0.
__device__ __forceinline__ int map_k1(int kp){
  if (kp < 120){ int g = kp/40, r = kp - g*40; return (r<36) ? g*36 + r : -1; }
  if (kp < 141) return kp - 12;   // 108 + (kp-120)
  return -1;
}

// ---------------- fused precompute: all 4 transposes in ONE launch ----------------
// blocks [0,3072)    : plane transpose (C,H,W) f32 -> (H,W,C40) bf16
// blocks [3072,3078) : line transpose (C,L) f32 -> (L,C40) bf16
// blocks [3078,3098) : W1 (129x256 f32) -> bf16 B-frags, K remapped/padded to 160
// blocks [3098,3122) : W2 (256x129 f32) -> bf16 B-frags, N padded to 192
#define NB_TP 3072
#define NB_TL 6
#define NB_W1 20
#define NB_W2 24
__global__ void k_pre(const float* __restrict__ planes, const float* __restrict__ lines,
                      const float* __restrict__ W1, const float* __restrict__ W2,
                      u16* __restrict__ pt, u16* __restrict__ lt,
                      u16* __restrict__ w1s, u16* __restrict__ w2s){
  const int b = blockIdx.x;
  const int tid = threadIdx.x;
  if (b < NB_TP){
    int t = b*256 + tid;                         // 0 .. 786431  (3*512*512)
    int i = t >> 18;
    int yx = t & 262143;
    const float* src = planes + (size_t)i*9437184 + yx;   // i*36*262144 + y*512 + x
    uint4* dst = reinterpret_cast<uint4*>(pt + (size_t)t*40);
#pragma unroll
    for (int cc=0; cc<5; cc++){
      float v[8];
#pragma unroll
      for (int e=0;e<8;e++){
        int c = cc*8+e;
        v[e] = (c<36) ? src[(size_t)c*262144] : 0.f;
      }
      uint4 o; o.x=pack2bf(v[0],v[1]); o.y=pack2bf(v[2],v[3]); o.z=pack2bf(v[4],v[5]); o.w=pack2bf(v[6],v[7]);
      dst[cc]=o;
    }
  } else if (b < NB_TP+NB_TL){
    int t = (b-NB_TP)*256 + tid;                 // 0 .. 1535 (3*512)
    int i = t >> 9, g = t & 511;
    const float* src = lines + (size_t)i*18432 + g;       // i*36*512 + g
    uint4* dst = reinterpret_cast<uint4*>(lt + (size_t)t*40);
#pragma unroll
    for (int cc=0; cc<5; cc++){
      float v[8];
#pragma unroll
      for (int e=0;e<8;e++){
        int c = cc*8+e;
        v[e] = (c<36) ? src[(size_t)c*512] : 0.f;
      }
      uint4 o; o.x=pack2bf(v[0],v[1]); o.y=pack2bf(v[2],v[3]); o.z=pack2bf(v[4],v[5]); o.w=pack2bf(v[6],v[7]);
      dst[cc]=o;
    }
  } else if (b < NB_TP+NB_TL+NB_W1){
    int t = (b-(NB_TP+NB_TL))*256 + tid;         // 0..5119 = 80 frags * 64 lanes
    int lane = t & 63;
    int fid = t >> 6;                            // nt*5 + kt
    int nt = fid/5, kt = fid - nt*5;
    int n = nt*16 + (lane & 15);
    int kb = kt*32 + (lane >> 4)*8;
    float v[8];
#pragma unroll
    for (int j=0;j<8;j++){ int k = map_k1(kb+j); v[j] = (k>=0) ? W1[k*256+n] : 0.f; }
    uint4 o; o.x=pack2bf(v[0],v[1]); o.y=pack2bf(v[2],v[3]); o.z=pack2bf(v[4],v[5]); o.w=pack2bf(v[6],v[7]);
    *reinterpret_cast<uint4*>(w1s + (size_t)t*8) = o;
  } else {
    int t = (b-(NB_TP+NB_TL+NB_W1))*256 + tid;   // 0..6143 = 96 frags * 64 lanes
    int lane = t & 63;
    int fid = t >> 6;                            // nt*8 + kt
    int kb = (fid & 7)*32 + (lane >> 4)*8;
    int n = (fid >> 3)*16 + (lane & 15);
    float v[8];
#pragma unroll
    for (int j=0;j<8;j++){ int k = kb+j; v[j] = (n<129) ? W2[k*129+n] : 0.f; }
    uint4 o; o.x=pack2bf(v[0],v[1]); o.y=pack2bf(v[2],v[3]); o.z=pack2bf(v[4],v[5]); o.w=pack2bf(v[6],v[7]);
    *reinterpret_cast<uint4*>(w2s + (size_t)t*8) = o;
  }
}

// unpack 2 packed bf16 -> float2 (2 VALU)
__device__ __forceinline__ f32x2 bfx2(u32 u){
  f32x2 r;
  r.x = __uint_as_float(u << 16);
  r.y = __uint_as_float(u & 0xffff0000u);
  return r;
}

// weight-form bilinear*line on 2 packed channels: 7 packed FLOP + 12 unpack + 3 pack
__device__ __forceinline__ u32 blend2(u32 u00,u32 u01,u32 u10,u32 u11,u32 g0,u32 g1,
                                      float w00,float w01,float w10,float w11,
                                      float v0,float v1){
  f32x2 pf = bfx2(u00)*w00 + bfx2(u01)*w01 + bfx2(u10)*w10 + bfx2(u11)*w11;
  f32x2 lf = bfx2(g0)*v0 + bfx2(g1)*v1;
  f32x2 r  = pf*lf;
  return pack2bf_fast(r.x, r.y);
}

#define FSTRIDE 168   // feature LDS row stride (u16), 336B: 84 dw -> 2-way bank alias only (free)
#define HSTRIDE 264   // H LDS row stride (u16), 528B: 132 dw -> 2-way alias only (free)

// ---------------- fused gather + MLP ----------------
// 512 threads = 8 waves, 64 points/block. 8 threads/point: q=0..5 gather
// (plane i=q>>1; part q&1 splits the 40-slot texel ASYMMETRICALLY so all loads
// are 16B-aligned dwordx4: part0 = ch 0..23 (3 x 16B), part1 = ch 24..39
// (2 x 16B); texel stride 80B = 5x16B keeps every chunk aligned). q=6 PE slots
// 120..139, q=7 PE slot 140 + zeros (slots 140..159 MUST be written: uninit LDS
// NaN x zero-weight still poisons the MFMA accumulator).
// Occupancy: ONE f32x4 acc[2][4] array serves BOTH MFMA stages (lifetimes are
// disjoint; the allocator does not overlap them on its own — r1 measured
// 48 VGPR + 56 AGPR = 104 regs -> 4 waves/SIMD, 44% occ). Reuse targets
// ~80 regs -> 6 waves/SIMD. launch_bounds min-waves=5 caps the allocator at
// ~102 so it cannot drift back.
__global__ void __launch_bounds__(512, 5) k_main(
    const float* __restrict__ xyz, const u16* __restrict__ pt,
    const u16* __restrict__ lt, const u16* __restrict__ w1s,
    const u16* __restrict__ w2s, const float* __restrict__ b1,
    const float* __restrict__ b2, float* __restrict__ out)
{
  __shared__ u16 smem[64*HSTRIDE];   // 33,792 B; feat-tile (stride 168) aliased by H-tile (stride 264)
  const int tid = threadIdx.x;
  const int p = tid >> 3, q = tid & 7;
  const int gp = blockIdx.x*64 + p;
  const float u0 = xyz[gp*3], u1 = xyz[gp*3+1], u2 = xyz[gp*3+2];
  const float xn0 = 2.f*u0-1.f, xn1 = 2.f*u1-1.f, xn2 = 2.f*u2-1.f;

  if (q < 6){
    const int i = q >> 1, part = q & 1;
    // MAT_MODE=[(0,1),(0,2),(1,2)], VEC_MODE=[2,1,0]; x<-m0, y<-m1
    float gxv, gyv, gzv;
    if      (i==0){ gxv=xn0; gyv=xn1; gzv=xn2; }
    else if (i==1){ gxv=xn0; gyv=xn2; gzv=xn1; }
    else          { gxv=xn1; gyv=xn2; gzv=xn0; }
    float px=(gxv+1.0f)*0.5f*511.0f, py=(gyv+1.0f)*0.5f*511.0f, pz=(gzv+1.0f)*0.5f*511.0f;
    float fx=fminf(fmaxf(floorf(px),0.f),510.f);
    float fy=fminf(fmaxf(floorf(py),0.f),510.f);
    float fz=fminf(fmaxf(floorf(pz),0.f),510.f);
    int ix=(int)fx, iy=(int)fy, iz=(int)fz;
    float wx=px-fx, wy=py-fy, wz=pz-fz;
    // weight-form: 4 fma/ch for bilinear, 2 for line
    const float cwx = 1.f-wx, cwy = 1.f-wy;
    const float w00 = cwx*cwy, w01 = wx*cwy, w10 = cwx*wy, w11 = wx*wy;
    const float v0 = 1.f-wz, v1 = wz;
    const int nch = part ? 2 : 3;              // 16B chunks this thread owns
    const u16* tb = pt + (size_t)((i<<18)+(iy<<9)+ix)*40 + part*24;
    const u16* lb = lt + (size_t)((i<<9)+iz)*40 + part*24;
    u16* dst = smem + p*FSTRIDE + i*40 + part*24;
#pragma unroll
    for (int ch=0; ch<3; ch++){
      if (ch < nch){
        uint4 a00 = *reinterpret_cast<const uint4*>(tb + ch*8);
        uint4 a01 = *reinterpret_cast<const uint4*>(tb + 40 + ch*8);
        uint4 a10 = *reinterpret_cast<const uint4*>(tb + 20480 + ch*8);
        uint4 a11 = *reinterpret_cast<const uint4*>(tb + 20520 + ch*8);
        uint4 e0  = *reinterpret_cast<const uint4*>(lb + ch*8);
        uint4 e1  = *reinterpret_cast<const uint4*>(lb + 40 + ch*8);
        uint4 o;
        o.x = blend2(a00.x,a01.x,a10.x,a11.x,e0.x,e1.x, w00,w01,w10,w11,v0,v1);
        o.y = blend2(a00.y,a01.y,a10.y,a11.y,e0.y,e1.y, w00,w01,w10,w11,v0,v1);
        o.z = blend2(a00.z,a01.z,a10.z,a11.z,e0.z,e1.z, w00,w01,w10,w11,v0,v1);
        o.w = blend2(a00.w,a01.w,a10.w,a11.w,e0.w,e1.w, w00,w01,w10,w11,v0,v1);
        *reinterpret_cast<uint4*>(dst + ch*8) = o;
      }
    }
  } else if (q == 6){
    // PE slots 120..139: [x(3), sin(x), cos(x), sin(2x), cos(2x), sin(4x), cos(4x)[0..1]]
    float v[20];
    v[0]=xn0; v[1]=xn1; v[2]=xn2;
    v[3]=__sinf(xn0);      v[4]=__sinf(xn1);      v[5]=__sinf(xn2);
    v[6]=__cosf(xn0);      v[7]=__cosf(xn1);      v[8]=__cosf(xn2);
    v[9]=__sinf(2.f*xn0);  v[10]=__sinf(2.f*xn1); v[11]=__sinf(2.f*xn2);
    v[12]=__cosf(2.f*xn0); v[13]=__cosf(2.f*xn1); v[14]=__cosf(2.f*xn2);
    v[15]=__sinf(4.f*xn0); v[16]=__sinf(4.f*xn1); v[17]=__sinf(4.f*xn2);
    v[18]=__cosf(4.f*xn0); v[19]=__cosf(4.f*xn1);
    u16* dst = smem + p*FSTRIDE + 120;
#pragma unroll
    for (int c=0; c<10; c++)
      *reinterpret_cast<u32*>(dst + c*2) = pack2bf_fast(v[c*2], v[c*2+1]);
  } else {
    // q==7: PE slot 140 = cos(4*xn2), slots 141..159 explicit zeros
    u16* dst = smem + p*FSTRIDE + 140;
    *reinterpret_cast<u32*>(dst) = pack2bf_fast(__cosf(4.f*xn2), 0.f);
#pragma unroll
    for (int c=1; c<10; c++)
      *reinterpret_cast<u32*>(dst + c*2) = 0u;
  }
  __syncthreads();

  // ---- stage 1: H = softplus(100*(feat@W1+b1))/100, M=64 K=160 N=256 ----
  const int lane = tid & 63;
  const int w = tid >> 6;            // 0..7
  const int wm = w & 1, wn = w >> 1; // 2 m-tiles x 4 n-tiles per wave
  const int lm = lane & 15;
  const int quad = lane >> 4;
  const f32x4 zero = {0.f,0.f,0.f,0.f};
  f32x4 acc[2][4];                   // SHARED between stage1 and stage2 (reg budget)
#pragma unroll
  for (int mt=0; mt<2; mt++)
#pragma unroll
    for (int nt=0; nt<4; nt++) acc[mt][nt] = zero;

#pragma unroll
  for (int kt=0; kt<5; kt++){
    short8 a[2];
#pragma unroll
    for (int mt=0; mt<2; mt++)
      a[mt] = *reinterpret_cast<const short8*>(smem + ((wm*2+mt)*16 + lm)*FSTRIDE + kt*32 + quad*8);
    short8 b[4];
#pragma unroll
    for (int nt=0; nt<4; nt++)
      b[nt] = *reinterpret_cast<const short8*>(w1s + (size_t)(((wn*4+nt)*5 + kt)*64 + lane)*8);
#pragma unroll
    for (int mt=0; mt<2; mt++)
#pragma unroll
      for (int nt=0; nt<4; nt++)
        acc[mt][nt] = __builtin_amdgcn_mfma_f32_16x16x32_bf16(a[mt], b[nt], acc[mt][nt], 0,0,0);
  }
  __syncthreads();   // all feat reads done before H overwrites the same LDS

#pragma unroll
  for (int nt=0; nt<4; nt++){
    int col = wn*64 + nt*16 + lm;
    float bias = b1[col];
#pragma unroll
    for (int mt=0; mt<2; mt++){
#pragma unroll
      for (int r=0; r<4; r++){
        float xv = acc[mt][nt][r] + bias;
        float z = 100.f*xv;
        float y = (z > 15.f) ? xv : __logf(1.f + __expf(z))*0.01f;
        int row = (wm*2+mt)*16 + quad*4 + r;
        smem[row*HSTRIDE + col] = f2bf_fast(y);
      }
    }
  }
  __syncthreads();

  // ---- stage 2: out = H@W2 + b2, M=64 K=256 N=144(->192 padded) ----
  // reuse acc[][0..2] (stage-1 values fully consumed above)
#pragma unroll
  for (int mt=0; mt<2; mt++)
#pragma unroll
    for (int nt=0; nt<3; nt++) acc[mt][nt] = zero;

#pragma unroll
  for (int kt=0; kt<8; kt++){
    short8 a[2];
#pragma unroll
    for (int mt=0; mt<2; mt++)
      a[mt] = *reinterpret_cast<const short8*>(smem + ((wm*2+mt)*16 + lm)*HSTRIDE + kt*32 + quad*8);
    short8 b[3];
#pragma unroll
    for (int nt=0; nt<3; nt++){
      int ntg = wn*3 + nt;
      b[nt] = *reinterpret_cast<const short8*>(w2s + (size_t)((ntg*8 + kt)*64 + lane)*8);
    }
#pragma unroll
    for (int mt=0; mt<2; mt++)
#pragma unroll
      for (int nt=0; nt<3; nt++)
        acc[mt][nt] = __builtin_amdgcn_mfma_f32_16x16x32_bf16(a[mt], b[nt], acc[mt][nt], 0,0,0);
  }

  // plain cached stores: L2 merges the 64B wave segments into full lines
  // (r1 measured: nontemporal doubled WRITE_SIZE 268->567MB, +27us)
#pragma unroll
  for (int nt=0; nt<3; nt++){
    int j = (wn*3 + nt)*16 + lm;
    if (j < 129){
      float bias = b2[j];
#pragma unroll
      for (int mt=0; mt<2; mt++){
#pragma unroll
        for (int r=0; r<4; r++){
          int row = (wm*2+mt)*16 + quad*4 + r;
          out[(size_t)(blockIdx.x*64 + row)*129 + j] = acc[mt][nt][r] + bias;
        }
      }
    }
  }
}

extern "C" void kernel_launch(void* const* d_in, const int* in_sizes, int n_in,
                              void* d_out, int out_size, void* d_ws, size_t ws_size,
                              hipStream_t stream) {
  const float* xyz    = (const float*)d_in[0];
  const float* planes = (const float*)d_in[1];
  const float* lines  = (const float*)d_in[2];
  const float* W1     = (const float*)d_in[3];
  const float* b1     = (const float*)d_in[4];
  const float* W2     = (const float*)d_in[5];
  const float* b2     = (const float*)d_in[6];
  if (ws_size < (size_t)WS_NEEDED) return;   // workspace too small: fail loudly (validation will show it)

  u16* pt  = (u16*)((char*)d_ws);
  u16* lt  = (u16*)((char*)d_ws + OFF_LINES_T);
  u16* w1s = (u16*)((char*)d_ws + OFF_W1S);
  u16* w2s = (u16*)((char*)d_ws + OFF_W2S);

  k_pre<<<NB_TP+NB_TL+NB_W1+NB_W2, 256, 0, stream>>>(planes, lines, W1, W2, pt, lt, w1s, w2s);
  k_main<<<8192, 512, 0, stream>>>(xyz, pt, lt, w1s, w2s, b1, b2, (float*)d_out);
}

// Round 3
// 601.789 us; speedup vs baseline: 1.1186x; 1.0738x over previous
//
#include <hip/hip_runtime.h>
#include <math.h>

typedef unsigned short u16;
typedef unsigned int u32;
typedef __attribute__((ext_vector_type(2))) u32 u32x2;
typedef __attribute__((ext_vector_type(8))) short short8;
typedef __attribute__((ext_vector_type(4))) float f32x4;
typedef __attribute__((ext_vector_type(2))) float f32x2;

// ---------------- workspace layout (bytes) ----------------
// planes_t: 3*512*512 texels * 40 bf16 ch (c>=36 zero)   = 62,914,560
// lines_t : 3*512 texels * 40 bf16                        =    122,880
// w1s     : 16 nt * 5 kt * 64 lanes * 8 bf16              =     81,920
// w2s     : 12 nt * 8 kt * 64 lanes * 8 bf16              =     98,304
#define OFF_LINES_T 62914560u
#define OFF_W1S     63037440u
#define OFF_W2S     63119360u
#define WS_NEEDED   63217664u

__device__ __forceinline__ float bf_lo(u32 u){ union{u32 i;float f;} v; v.i = u << 16; return v.f; }
__device__ __forceinline__ float bf_hi(u32 u){ union{u32 i;float f;} v; v.i = u & 0xffff0000u; return v.f; }
// RTNE pack (precompute kernels only — cost irrelevant there)
__device__ __forceinline__ u16 f2bf(float f){ union{float f;u32 i;} v; v.f=f; u32 i=v.i; return (u16)((i + 0x7fffu + ((i>>16)&1u)) >> 16); }
__device__ __forceinline__ u32 pack2bf(float lo, float hi){ return (u32)f2bf(lo) | ((u32)f2bf(hi)<<16); }
// fast round-half-up pack: 2 adds + v_perm (vs ~9 inst RTNE); error <= 0.5 ulp
__device__ __forceinline__ u32 pack2bf_fast(float lo, float hi){
  return __builtin_amdgcn_perm(__float_as_uint(hi) + 0x8000u,
                               __float_as_uint(lo) + 0x8000u, 0x07060302u);
}
__device__ __forceinline__ u16 f2bf_fast(float f){ return (u16)((__float_as_uint(f) + 0x8000u) >> 16); }

// LDS k'-layout (160 slots): [0..35]=mode0, [36..39]=0, [40..75]=mode1, [76..79]=0,
// [80..115]=mode2, [116..119]=0, [120..140]=PE(21), [141..159]=0.
__device__ __forceinline__ int map_k1(int kp){
  if (kp < 120){ int g = kp/40, r = kp - g*40; return (r<36) ? g*36 + r : -1; }
  if (kp < 141) return kp - 12;   // 108 + (kp-120)
  return -1;
}

// ---------------- fused precompute: all 4 transposes in ONE launch ----------------
#define NB_TP 3072
#define NB_TL 6
#define NB_W1 20
#define NB_W2 24
__global__ void k_pre(const float* __restrict__ planes, const float* __restrict__ lines,
                      const float* __restrict__ W1, const float* __restrict__ W2,
                      u16* __restrict__ pt, u16* __restrict__ lt,
                      u16* __restrict__ w1s, u16* __restrict__ w2s){
  const int b = blockIdx.x;
  const int tid = threadIdx.x;
  if (b < NB_TP){
    int t = b*256 + tid;                         // 0 .. 786431  (3*512*512)
    int i = t >> 18;
    int yx = t & 262143;
    const float* src = planes + (size_t)i*9437184 + yx;   // i*36*262144 + y*512 + x
    uint4* dst = reinterpret_cast<uint4*>(pt + (size_t)t*40);
#pragma unroll
    for (int cc=0; cc<5; cc++){
      float v[8];
#pragma unroll
      for (int e=0;e<8;e++){
        int c = cc*8+e;
        v[e] = (c<36) ? src[(size_t)c*262144] : 0.f;
      }
      uint4 o; o.x=pack2bf(v[0],v[1]); o.y=pack2bf(v[2],v[3]); o.z=pack2bf(v[4],v[5]); o.w=pack2bf(v[6],v[7]);
      dst[cc]=o;
    }
  } else if (b < NB_TP+NB_TL){
    int t = (b-NB_TP)*256 + tid;                 // 0 .. 1535 (3*512)
    int i = t >> 9, g = t & 511;
    const float* src = lines + (size_t)i*18432 + g;       // i*36*512 + g
    uint4* dst = reinterpret_cast<uint4*>(lt + (size_t)t*40);
#pragma unroll
    for (int cc=0; cc<5; cc++){
      float v[8];
#pragma unroll
      for (int e=0;e<8;e++){
        int c = cc*8+e;
        v[e] = (c<36) ? src[(size_t)c*512] : 0.f;
      }
      uint4 o; o.x=pack2bf(v[0],v[1]); o.y=pack2bf(v[2],v[3]); o.z=pack2bf(v[4],v[5]); o.w=pack2bf(v[6],v[7]);
      dst[cc]=o;
    }
  } else if (b < NB_TP+NB_TL+NB_W1){
    int t = (b-(NB_TP+NB_TL))*256 + tid;         // 0..5119 = 80 frags * 64 lanes
    int lane = t & 63;
    int fid = t >> 6;                            // nt*5 + kt
    int nt = fid/5, kt = fid - nt*5;
    int n = nt*16 + (lane & 15);
    int kb = kt*32 + (lane >> 4)*8;
    float v[8];
#pragma unroll
    for (int j=0;j<8;j++){ int k = map_k1(kb+j); v[j] = (k>=0) ? W1[k*256+n] : 0.f; }
    uint4 o; o.x=pack2bf(v[0],v[1]); o.y=pack2bf(v[2],v[3]); o.z=pack2bf(v[4],v[5]); o.w=pack2bf(v[6],v[7]);
    *reinterpret_cast<uint4*>(w1s + (size_t)t*8) = o;
  } else {
    int t = (b-(NB_TP+NB_TL+NB_W1))*256 + tid;   // 0..6143 = 96 frags * 64 lanes
    int lane = t & 63;
    int fid = t >> 6;                            // nt*8 + kt
    int kb = (fid & 7)*32 + (lane >> 4)*8;
    int n = (fid >> 3)*16 + (lane & 15);
    float v[8];
#pragma unroll
    for (int j=0;j<8;j++){ int k = kb+j; v[j] = (n<129) ? W2[k*129+n] : 0.f; }
    uint4 o; o.x=pack2bf(v[0],v[1]); o.y=pack2bf(v[2],v[3]); o.z=pack2bf(v[4],v[5]); o.w=pack2bf(v[6],v[7]);
    *reinterpret_cast<uint4*>(w2s + (size_t)t*8) = o;
  }
}

// unpack 2 packed bf16 -> float2 (2 VALU)
__device__ __forceinline__ f32x2 bfx2(u32 u){
  f32x2 r;
  r.x = __uint_as_float(u << 16);
  r.y = __uint_as_float(u & 0xffff0000u);
  return r;
}

// weight-form bilinear*line on 2 packed channels
__device__ __forceinline__ u32 blend2(u32 u00,u32 u01,u32 u10,u32 u11,u32 g0,u32 g1,
                                      float w00,float w01,float w10,float w11,
                                      float v0,float v1){
  f32x2 pf = bfx2(u00)*w00 + bfx2(u01)*w01 + bfx2(u10)*w10 + bfx2(u11)*w11;
  f32x2 lf = bfx2(g0)*v0 + bfx2(g1)*v1;
  f32x2 r  = pf*lf;
  return pack2bf_fast(r.x, r.y);
}

#define FSTRIDE 168   // feature LDS row stride (u16), 336B
#define HSTRIDE 264   // H LDS row stride (u16), 528B

// ---------------- fused gather + MLP, 256 threads / 32 points ----------------
// r0-r2 evidence: all pipe-local changes null (VALU 49%, MFMA 12%, HBM 26%,
// Occ 45% pinned) -> phase-serialization-bound: with 512-thr blocks only 2
// blocks/CU are resident, and gather (memory phase) and MLP (compute phase)
// are barrier-locked within a block, so HBM idles during MLP and MFMA idles
// during gather. Fix: 256-thr / 32-point blocks -> SAME 16 waves/CU but as 4
// INDEPENDENT blocks whose phases interleave. LDS 16.9KB (9 blocks' worth);
// registers bind at 4 blocks (48 VGPR + 56 AGPR = 104 -> 4 waves/SIMD).
// sched_barrier(0) between stage-1 epilogue and stage-2 init stops the pre-RA
// scheduler hoisting stage-2's accvgpr zero-inits above the epilogue's acc
// reads (that hoist is what kept stage1/stage2 AGPRs from coalescing in r2);
// if RA then reuses them: 80 regs -> 6 waves/SIMD -> 6 blocks/CU.
__global__ void __launch_bounds__(256, 4) k_main(
    const float* __restrict__ xyz, const u16* __restrict__ pt,
    const u16* __restrict__ lt, const u16* __restrict__ w1s,
    const u16* __restrict__ w2s, const float* __restrict__ b1,
    const float* __restrict__ b2, float* __restrict__ out)
{
  __shared__ __align__(16) u16 smem[32*HSTRIDE];   // 16,896 B; feat (stride 168) aliased by H (stride 264)
  const int tid = threadIdx.x;
  const int p = tid >> 3, q = tid & 7;             // 32 points, 8 roles
  const int gp = blockIdx.x*32 + p;
  const float u0 = xyz[gp*3], u1 = xyz[gp*3+1], u2 = xyz[gp*3+2];
  const float xn0 = 2.f*u0-1.f, xn1 = 2.f*u1-1.f, xn2 = 2.f*u2-1.f;

  if (q < 6){
    const int i = q >> 1, part = q & 1;
    // MAT_MODE=[(0,1),(0,2),(1,2)], VEC_MODE=[2,1,0]; x<-m0, y<-m1
    float gxv, gyv, gzv;
    if      (i==0){ gxv=xn0; gyv=xn1; gzv=xn2; }
    else if (i==1){ gxv=xn0; gyv=xn2; gzv=xn1; }
    else          { gxv=xn1; gyv=xn2; gzv=xn0; }
    float px=(gxv+1.0f)*0.5f*511.0f, py=(gyv+1.0f)*0.5f*511.0f, pz=(gzv+1.0f)*0.5f*511.0f;
    float fx=fminf(fmaxf(floorf(px),0.f),510.f);
    float fy=fminf(fmaxf(floorf(py),0.f),510.f);
    float fz=fminf(fmaxf(floorf(pz),0.f),510.f);
    int ix=(int)fx, iy=(int)fy, iz=(int)fz;
    float wx=px-fx, wy=py-fy, wz=pz-fz;
    const float cwx = 1.f-wx, cwy = 1.f-wy;
    const float w00 = cwx*cwy, w01 = wx*cwy, w10 = cwx*wy, w11 = wx*wy;
    const float v0 = 1.f-wz, v1 = wz;
    const int nch = part ? 2 : 3;              // 16B chunks this thread owns (asym 24/16 split)
    const u16* tb = pt + (size_t)((i<<18)+(iy<<9)+ix)*40 + part*24;
    const u16* lb = lt + (size_t)((i<<9)+iz)*40 + part*24;
    u16* dst = smem + p*FSTRIDE + i*40 + part*24;
#pragma unroll
    for (int ch=0; ch<3; ch++){
      if (ch < nch){
        uint4 a00 = *reinterpret_cast<const uint4*>(tb + ch*8);
        uint4 a01 = *reinterpret_cast<const uint4*>(tb + 40 + ch*8);
        uint4 a10 = *reinterpret_cast<const uint4*>(tb + 20480 + ch*8);
        uint4 a11 = *reinterpret_cast<const uint4*>(tb + 20520 + ch*8);
        uint4 e0  = *reinterpret_cast<const uint4*>(lb + ch*8);
        uint4 e1  = *reinterpret_cast<const uint4*>(lb + 40 + ch*8);
        uint4 o;
        o.x = blend2(a00.x,a01.x,a10.x,a11.x,e0.x,e1.x, w00,w01,w10,w11,v0,v1);
        o.y = blend2(a00.y,a01.y,a10.y,a11.y,e0.y,e1.y, w00,w01,w10,w11,v0,v1);
        o.z = blend2(a00.z,a01.z,a10.z,a11.z,e0.z,e1.z, w00,w01,w10,w11,v0,v1);
        o.w = blend2(a00.w,a01.w,a10.w,a11.w,e0.w,e1.w, w00,w01,w10,w11,v0,v1);
        *reinterpret_cast<uint4*>(dst + ch*8) = o;
      }
    }
  } else if (q == 6){
    // PE slots 120..139
    float v[20];
    v[0]=xn0; v[1]=xn1; v[2]=xn2;
    v[3]=__sinf(xn0);      v[4]=__sinf(xn1);      v[5]=__sinf(xn2);
    v[6]=__cosf(xn0);      v[7]=__cosf(xn1);      v[8]=__cosf(xn2);
    v[9]=__sinf(2.f*xn0);  v[10]=__sinf(2.f*xn1); v[11]=__sinf(2.f*xn2);
    v[12]=__cosf(2.f*xn0); v[13]=__cosf(2.f*xn1); v[14]=__cosf(2.f*xn2);
    v[15]=__sinf(4.f*xn0); v[16]=__sinf(4.f*xn1); v[17]=__sinf(4.f*xn2);
    v[18]=__cosf(4.f*xn0); v[19]=__cosf(4.f*xn1);
    u16* dst = smem + p*FSTRIDE + 120;
#pragma unroll
    for (int c=0; c<10; c++)
      *reinterpret_cast<u32*>(dst + c*2) = pack2bf_fast(v[c*2], v[c*2+1]);
  } else {
    // q==7: PE slot 140 = cos(4*xn2), slots 141..159 explicit zeros
    u16* dst = smem + p*FSTRIDE + 140;
    *reinterpret_cast<u32*>(dst) = pack2bf_fast(__cosf(4.f*xn2), 0.f);
#pragma unroll
    for (int c=1; c<10; c++)
      *reinterpret_cast<u32*>(dst + c*2) = 0u;
  }
  __syncthreads();

  // ---- stage 1: H = softplus(100*(feat@W1+b1))/100, M=32 K=160 N=256 ----
  // 4 waves: wave w owns n-tiles w*4..w*4+3, both m-tiles. acc[2][4] = 32 AGPR.
  const int lane = tid & 63;
  const int w = tid >> 6;            // 0..3
  const int lm = lane & 15;
  const int quad = lane >> 4;
  const f32x4 zero = {0.f,0.f,0.f,0.f};
  f32x4 acc[2][4];                   // shared between stage1 and stage2
#pragma unroll
  for (int mt=0; mt<2; mt++)
#pragma unroll
    for (int nt=0; nt<4; nt++) acc[mt][nt] = zero;

#pragma unroll
  for (int kt=0; kt<5; kt++){
    short8 a[2];
#pragma unroll
    for (int mt=0; mt<2; mt++)
      a[mt] = *reinterpret_cast<const short8*>(smem + (mt*16 + lm)*FSTRIDE + kt*32 + quad*8);
    short8 b[4];
#pragma unroll
    for (int nt=0; nt<4; nt++)
      b[nt] = *reinterpret_cast<const short8*>(w1s + (size_t)(((w*4+nt)*5 + kt)*64 + lane)*8);
#pragma unroll
    for (int mt=0; mt<2; mt++)
#pragma unroll
      for (int nt=0; nt<4; nt++)
        acc[mt][nt] = __builtin_amdgcn_mfma_f32_16x16x32_bf16(a[mt], b[nt], acc[mt][nt], 0,0,0);
  }
  __syncthreads();   // all feat reads done before H overwrites the same LDS

#pragma unroll
  for (int nt=0; nt<4; nt++){
    int col = w*64 + nt*16 + lm;
    float bias = b1[col];
#pragma unroll
    for (int mt=0; mt<2; mt++){
#pragma unroll
      for (int r=0; r<4; r++){
        float xv = acc[mt][nt][r] + bias;
        float z = 100.f*xv;
        float y = (z > 15.f) ? xv : __logf(1.f + __expf(z))*0.01f;
        int row = mt*16 + quad*4 + r;
        smem[row*HSTRIDE + col] = f2bf_fast(y);
      }
    }
  }
  // stop the pre-RA scheduler hoisting stage-2 accvgpr zero-inits above the
  // epilogue's acc reads (lifetime overlap = no AGPR coalescing, r2 evidence)
  __builtin_amdgcn_sched_barrier(0);
  __syncthreads();

  // ---- stage 2: out = H@W2 + b2, M=32 K=256 N=144(->192 padded) ----
  // wave w owns n-tiles w*3..w*3+2. acc reuse: [2][3] of the same array.
#pragma unroll
  for (int mt=0; mt<2; mt++)
#pragma unroll
    for (int nt=0; nt<3; nt++) acc[mt][nt] = zero;

#pragma unroll
  for (int kt=0; kt<8; kt++){
    short8 a[2];
#pragma unroll
    for (int mt=0; mt<2; mt++)
      a[mt] = *reinterpret_cast<const short8*>(smem + (mt*16 + lm)*HSTRIDE + kt*32 + quad*8);
    short8 b[3];
#pragma unroll
    for (int nt=0; nt<3; nt++){
      int ntg = w*3 + nt;
      b[nt] = *reinterpret_cast<const short8*>(w2s + (size_t)((ntg*8 + kt)*64 + lane)*8);
    }
#pragma unroll
    for (int mt=0; mt<2; mt++)
#pragma unroll
      for (int nt=0; nt<3; nt++)
        acc[mt][nt] = __builtin_amdgcn_mfma_f32_16x16x32_bf16(a[mt], b[nt], acc[mt][nt], 0,0,0);
  }

  // plain cached stores (r1: nontemporal doubled WRITE_SIZE)
#pragma unroll
  for (int nt=0; nt<3; nt++){
    int j = (w*3 + nt)*16 + lm;
    if (j < 129){
      float bias = b2[j];
#pragma unroll
      for (int mt=0; mt<2; mt++){
#pragma unroll
        for (int r=0; r<4; r++){
          int row = mt*16 + quad*4 + r;
          out[(size_t)(blockIdx.x*32 + row)*129 + j] = acc[mt][nt][r] + bias;
        }
      }
    }
  }
}

extern "C" void kernel_launch(void* const* d_in, const int* in_sizes, int n_in,
                              void* d_out, int out_size, void* d_ws, size_t ws_size,
                              hipStream_t stream) {
  const float* xyz    = (const float*)d_in[0];
  const float* planes = (const float*)d_in[1];
  const float* lines  = (const float*)d_in[2];
  const float* W1     = (const float*)d_in[3];
  const float* b1     = (const float*)d_in[4];
  const float* W2     = (const float*)d_in[5];
  const float* b2     = (const float*)d_in[6];
  if (ws_size < (size_t)WS_NEEDED) return;   // workspace too small: fail loudly

  u16* pt  = (u16*)((char*)d_ws);
  u16* lt  = (u16*)((char*)d_ws + OFF_LINES_T);
  u16* w1s = (u16*)((char*)d_ws + OFF_W1S);
  u16* w2s = (u16*)((char*)d_ws + OFF_W2S);

  k_pre<<<NB_TP+NB_TL+NB_W1+NB_W2, 256, 0, stream>>>(planes, lines, W1, W2, pt, lt, w1s, w2s);
  k_main<<<16384, 256, 0, stream>>>(xyz, pt, lt, w1s, w2s, b1, b2, (float*)d_out);
}

// Round 4
// 598.751 us; speedup vs baseline: 1.1242x; 1.0051x over previous
//
#include <hip/hip_runtime.h>
#include <math.h>

typedef unsigned short u16;
typedef unsigned int u32;
typedef __attribute__((ext_vector_type(2))) u32 u32x2;
typedef __attribute__((ext_vector_type(8))) short short8;
typedef __attribute__((ext_vector_type(4))) float f32x4;
typedef __attribute__((ext_vector_type(2))) float f32x2;

// ---------------- workspace layout (bytes) ----------------
// planes_t: 3*512*512 texels * 40 bf16 ch (c>=36 zero)   = 62,914,560
// lines_t : 3*512 texels * 40 bf16                        =    122,880
// w1s     : 16 nt * 5 kt * 64 lanes * 8 bf16              =     81,920
// w2s     : 12 nt * 8 kt * 64 lanes * 8 bf16              =     98,304
#define OFF_LINES_T 62914560u
#define OFF_W1S     63037440u
#define OFF_W2S     63119360u
#define WS_NEEDED   63217664u

__device__ __forceinline__ float bf_lo(u32 u){ union{u32 i;float f;} v; v.i = u << 16; return v.f; }
__device__ __forceinline__ float bf_hi(u32 u){ union{u32 i;float f;} v; v.i = u & 0xffff0000u; return v.f; }
// RTNE pack (precompute kernels only — cost irrelevant there)
__device__ __forceinline__ u16 f2bf(float f){ union{float f;u32 i;} v; v.f=f; u32 i=v.i; return (u16)((i + 0x7fffu + ((i>>16)&1u)) >> 16); }
__device__ __forceinline__ u32 pack2bf(float lo, float hi){ return (u32)f2bf(lo) | ((u32)f2bf(hi)<<16); }
// fast round-half-up pack: 2 adds + v_perm (vs ~9 inst RTNE); error <= 0.5 ulp
__device__ __forceinline__ u32 pack2bf_fast(float lo, float hi){
  return __builtin_amdgcn_perm(__float_as_uint(hi) + 0x8000u,
                               __float_as_uint(lo) + 0x8000u, 0x07060302u);
}
__device__ __forceinline__ u16 f2bf_fast(float f){ return (u16)((__float_as_uint(f) + 0x8000u) >> 16); }

// LDS k'-layout (160 slots): [0..35]=mode0, [36..39]=0, [40..75]=mode1, [76..79]=0,
// [80..115]=mode2, [116..119]=0, [120..140]=PE(21), [141..159]=0.
__device__ __forceinline__ int map_k1(int kp){
  if (kp < 120){ int g = kp/40, r = kp - g*40; return (r<36) ? g*36 + r : -1; }
  if (kp < 141) return kp - 12;   // 108 + (kp-120)
  return -1;
}

// ---------------- fused precompute: all transposes in ONE launch ----------------
// r3 finding: total - k_main ~= 295us every round while k_pre's roofline is
// ~28us -> k_pre is ~10x off roofline. Suspect: output-texel-per-thread
// mapping stores 5 x 16B at 80B lane stride (each store instr spans ~80 cache
// lines, ~16x the transactions of a coalesced stream). Fix: one thread per
// OUTPUT 16B CHUNK (m = chunk id; texel = m/5, cc = m%5). Stores are
// lane-consecutive (4KB/wave dwordx4 streams). Reads: lanes sharing a channel
// (every 5th lane, ~13 lanes) read ~52B contiguous -> ~5-8 segments/instr,
// near-coalesced, and leftover bytes are next wave's L2 hits.
// blocks [0,15360)        : plane chunks (3*512*512*5 / 256)
// blocks [15360,15390)    : line chunks  (3*512*5 / 256)
// blocks [15390,15410)    : W1 frags
// blocks [15410,15434)    : W2 frags
#define NB_TP 15360
#define NB_TL 30
#define NB_W1 20
#define NB_W2 24
__global__ void k_pre(const float* __restrict__ planes, const float* __restrict__ lines,
                      const float* __restrict__ W1, const float* __restrict__ W2,
                      u16* __restrict__ pt, u16* __restrict__ lt,
                      u16* __restrict__ w1s, u16* __restrict__ w2s){
  const int b = blockIdx.x;
  const int tid = threadIdx.x;
  if (b < NB_TP){
    int m = b*256 + tid;                // chunk id 0..3,932,159
    int tt = m/5, cc = m - tt*5;        // texel 0..786431, chunk-in-texel 0..4
    int i = tt >> 18;
    int yx = tt & 262143;
    const float* src = planes + (size_t)i*9437184 + yx;   // i*36*262144 + y*512 + x
    int cbase = cc*8;
    float v[8];
#pragma unroll
    for (int e=0;e<8;e++) v[e] = 0.f;
    if (cc < 4){
#pragma unroll
      for (int e=0;e<8;e++) v[e] = src[(size_t)(cbase+e)*262144];
    } else {
#pragma unroll
      for (int e=0;e<4;e++) v[e] = src[(size_t)(32+e)*262144];
    }
    uint4 o; o.x=pack2bf(v[0],v[1]); o.y=pack2bf(v[2],v[3]); o.z=pack2bf(v[4],v[5]); o.w=pack2bf(v[6],v[7]);
    *reinterpret_cast<uint4*>(pt + (size_t)m*8) = o;      // byte m*16: lane-consecutive
  } else if (b < NB_TP+NB_TL){
    int m = (b-NB_TP)*256 + tid;        // chunk id 0..7679
    int tt = m/5, cc = m - tt*5;        // texel 0..1535
    int i = tt >> 9, g = tt & 511;
    const float* src = lines + (size_t)i*18432 + g;       // i*36*512 + g
    int cbase = cc*8;
    float v[8];
#pragma unroll
    for (int e=0;e<8;e++) v[e] = 0.f;
    if (cc < 4){
#pragma unroll
      for (int e=0;e<8;e++) v[e] = src[(size_t)(cbase+e)*512];
    } else {
#pragma unroll
      for (int e=0;e<4;e++) v[e] = src[(size_t)(32+e)*512];
    }
    uint4 o; o.x=pack2bf(v[0],v[1]); o.y=pack2bf(v[2],v[3]); o.z=pack2bf(v[4],v[5]); o.w=pack2bf(v[6],v[7]);
    *reinterpret_cast<uint4*>(lt + (size_t)m*8) = o;
  } else if (b < NB_TP+NB_TL+NB_W1){
    int t = (b-(NB_TP+NB_TL))*256 + tid;         // 0..5119 = 80 frags * 64 lanes
    int lane = t & 63;
    int fid = t >> 6;                            // nt*5 + kt
    int nt = fid/5, kt = fid - nt*5;
    int n = nt*16 + (lane & 15);
    int kb = kt*32 + (lane >> 4)*8;
    float v[8];
#pragma unroll
    for (int j=0;j<8;j++){ int k = map_k1(kb+j); v[j] = (k>=0) ? W1[k*256+n] : 0.f; }
    uint4 o; o.x=pack2bf(v[0],v[1]); o.y=pack2bf(v[2],v[3]); o.z=pack2bf(v[4],v[5]); o.w=pack2bf(v[6],v[7]);
    *reinterpret_cast<uint4*>(w1s + (size_t)t*8) = o;
  } else {
    int t = (b-(NB_TP+NB_TL+NB_W1))*256 + tid;   // 0..6143 = 96 frags * 64 lanes
    int lane = t & 63;
    int fid = t >> 6;                            // nt*8 + kt
    int kb = (fid & 7)*32 + (lane >> 4)*8;
    int n = (fid >> 3)*16 + (lane & 15);
    float v[8];
#pragma unroll
    for (int j=0;j<8;j++){ int k = kb+j; v[j] = (n<129) ? W2[k*129+n] : 0.f; }
    uint4 o; o.x=pack2bf(v[0],v[1]); o.y=pack2bf(v[2],v[3]); o.z=pack2bf(v[4],v[5]); o.w=pack2bf(v[6],v[7]);
    *reinterpret_cast<uint4*>(w2s + (size_t)t*8) = o;
  }
}

// unpack 2 packed bf16 -> float2 (2 VALU)
__device__ __forceinline__ f32x2 bfx2(u32 u){
  f32x2 r;
  r.x = __uint_as_float(u << 16);
  r.y = __uint_as_float(u & 0xffff0000u);
  return r;
}

// weight-form bilinear*line on 2 packed channels
__device__ __forceinline__ u32 blend2(u32 u00,u32 u01,u32 u10,u32 u11,u32 g0,u32 g1,
                                      float w00,float w01,float w10,float w11,
                                      float v0,float v1){
  f32x2 pf = bfx2(u00)*w00 + bfx2(u01)*w01 + bfx2(u10)*w10 + bfx2(u11)*w11;
  f32x2 lf = bfx2(g0)*v0 + bfx2(g1)*v1;
  f32x2 r  = pf*lf;
  return pack2bf_fast(r.x, r.y);
}

#define FSTRIDE 168   // feature LDS row stride (u16), 336B
#define HSTRIDE 264   // H LDS row stride (u16), 528B

// ---------------- fused gather + MLP, 256 threads / 32 points ----------------
// r3: 256-thr blocks (4 independent blocks/CU) bought 332->307us via phase
// decorrelation. Occ 53% = 4 waves/SIMD = 104 regs (48 VGPR + 56 AGPR; the
// sched_barrier AGPR-coalescing attempt did not land). HW occupancy steps at
// ~512/waves regs: 5 waves needs <=102 — we are 2 regs over. Force it:
// __launch_bounds__(256,5) caps the allocator at 102; worst case a trivial
// spill, best case +25% resident waves on a latency-bound kernel.
__global__ void __launch_bounds__(256, 5) k_main(
    const float* __restrict__ xyz, const u16* __restrict__ pt,
    const u16* __restrict__ lt, const u16* __restrict__ w1s,
    const u16* __restrict__ w2s, const float* __restrict__ b1,
    const float* __restrict__ b2, float* __restrict__ out)
{
  __shared__ __align__(16) u16 smem[32*HSTRIDE];   // 16,896 B; feat (stride 168) aliased by H (stride 264)
  const int tid = threadIdx.x;
  const int p = tid >> 3, q = tid & 7;             // 32 points, 8 roles
  const int gp = blockIdx.x*32 + p;
  const float u0 = xyz[gp*3], u1 = xyz[gp*3+1], u2 = xyz[gp*3+2];
  const float xn0 = 2.f*u0-1.f, xn1 = 2.f*u1-1.f, xn2 = 2.f*u2-1.f;

  if (q < 6){
    const int i = q >> 1, part = q & 1;
    // MAT_MODE=[(0,1),(0,2),(1,2)], VEC_MODE=[2,1,0]; x<-m0, y<-m1
    float gxv, gyv, gzv;
    if      (i==0){ gxv=xn0; gyv=xn1; gzv=xn2; }
    else if (i==1){ gxv=xn0; gyv=xn2; gzv=xn1; }
    else          { gxv=xn1; gyv=xn2; gzv=xn0; }
    float px=(gxv+1.0f)*0.5f*511.0f, py=(gyv+1.0f)*0.5f*511.0f, pz=(gzv+1.0f)*0.5f*511.0f;
    float fx=fminf(fmaxf(floorf(px),0.f),510.f);
    float fy=fminf(fmaxf(floorf(py),0.f),510.f);
    float fz=fminf(fmaxf(floorf(pz),0.f),510.f);
    int ix=(int)fx, iy=(int)fy, iz=(int)fz;
    float wx=px-fx, wy=py-fy, wz=pz-fz;
    const float cwx = 1.f-wx, cwy = 1.f-wy;
    const float w00 = cwx*cwy, w01 = wx*cwy, w10 = cwx*wy, w11 = wx*wy;
    const float v0 = 1.f-wz, v1 = wz;
    const int nch = part ? 2 : 3;              // 16B chunks this thread owns (asym 24/16 split)
    const u16* tb = pt + (size_t)((i<<18)+(iy<<9)+ix)*40 + part*24;
    const u16* lb = lt + (size_t)((i<<9)+iz)*40 + part*24;
    u16* dst = smem + p*FSTRIDE + i*40 + part*24;
#pragma unroll
    for (int ch=0; ch<3; ch++){
      if (ch < nch){
        uint4 a00 = *reinterpret_cast<const uint4*>(tb + ch*8);
        uint4 a01 = *reinterpret_cast<const uint4*>(tb + 40 + ch*8);
        uint4 a10 = *reinterpret_cast<const uint4*>(tb + 20480 + ch*8);
        uint4 a11 = *reinterpret_cast<const uint4*>(tb + 20520 + ch*8);
        uint4 e0  = *reinterpret_cast<const uint4*>(lb + ch*8);
        uint4 e1  = *reinterpret_cast<const uint4*>(lb + 40 + ch*8);
        uint4 o;
        o.x = blend2(a00.x,a01.x,a10.x,a11.x,e0.x,e1.x, w00,w01,w10,w11,v0,v1);
        o.y = blend2(a00.y,a01.y,a10.y,a11.y,e0.y,e1.y, w00,w01,w10,w11,v0,v1);
        o.z = blend2(a00.z,a01.z,a10.z,a11.z,e0.z,e1.z, w00,w01,w10,w11,v0,v1);
        o.w = blend2(a00.w,a01.w,a10.w,a11.w,e0.w,e1.w, w00,w01,w10,w11,v0,v1);
        *reinterpret_cast<uint4*>(dst + ch*8) = o;
      }
    }
  } else if (q == 6){
    // PE slots 120..139
    float v[20];
    v[0]=xn0; v[1]=xn1; v[2]=xn2;
    v[3]=__sinf(xn0);      v[4]=__sinf(xn1);      v[5]=__sinf(xn2);
    v[6]=__cosf(xn0);      v[7]=__cosf(xn1);      v[8]=__cosf(xn2);
    v[9]=__sinf(2.f*xn0);  v[10]=__sinf(2.f*xn1); v[11]=__sinf(2.f*xn2);
    v[12]=__cosf(2.f*xn0); v[13]=__cosf(2.f*xn1); v[14]=__cosf(2.f*xn2);
    v[15]=__sinf(4.f*xn0); v[16]=__sinf(4.f*xn1); v[17]=__sinf(4.f*xn2);
    v[18]=__cosf(4.f*xn0); v[19]=__cosf(4.f*xn1);
    u16* dst = smem + p*FSTRIDE + 120;
#pragma unroll
    for (int c=0; c<10; c++)
      *reinterpret_cast<u32*>(dst + c*2) = pack2bf_fast(v[c*2], v[c*2+1]);
  } else {
    // q==7: PE slot 140 = cos(4*xn2), slots 141..159 explicit zeros
    u16* dst = smem + p*FSTRIDE + 140;
    *reinterpret_cast<u32*>(dst) = pack2bf_fast(__cosf(4.f*xn2), 0.f);
#pragma unroll
    for (int c=1; c<10; c++)
      *reinterpret_cast<u32*>(dst + c*2) = 0u;
  }
  __syncthreads();

  // ---- stage 1: H = softplus(100*(feat@W1+b1))/100, M=32 K=160 N=256 ----
  // 4 waves: wave w owns n-tiles w*4..w*4+3, both m-tiles. acc[2][4] = 32 AGPR.
  const int lane = tid & 63;
  const int w = tid >> 6;            // 0..3
  const int lm = lane & 15;
  const int quad = lane >> 4;
  const f32x4 zero = {0.f,0.f,0.f,0.f};
  f32x4 acc[2][4];                   // shared between stage1 and stage2
#pragma unroll
  for (int mt=0; mt<2; mt++)
#pragma unroll
    for (int nt=0; nt<4; nt++) acc[mt][nt] = zero;

#pragma unroll
  for (int kt=0; kt<5; kt++){
    short8 a[2];
#pragma unroll
    for (int mt=0; mt<2; mt++)
      a[mt] = *reinterpret_cast<const short8*>(smem + (mt*16 + lm)*FSTRIDE + kt*32 + quad*8);
    short8 b[4];
#pragma unroll
    for (int nt=0; nt<4; nt++)
      b[nt] = *reinterpret_cast<const short8*>(w1s + (size_t)(((w*4+nt)*5 + kt)*64 + lane)*8);
#pragma unroll
    for (int mt=0; mt<2; mt++)
#pragma unroll
      for (int nt=0; nt<4; nt++)
        acc[mt][nt] = __builtin_amdgcn_mfma_f32_16x16x32_bf16(a[mt], b[nt], acc[mt][nt], 0,0,0);
  }
  __syncthreads();   // all feat reads done before H overwrites the same LDS

#pragma unroll
  for (int nt=0; nt<4; nt++){
    int col = w*64 + nt*16 + lm;
    float bias = b1[col];
#pragma unroll
    for (int mt=0; mt<2; mt++){
#pragma unroll
      for (int r=0; r<4; r++){
        float xv = acc[mt][nt][r] + bias;
        float z = 100.f*xv;
        float y = (z > 15.f) ? xv : __logf(1.f + __expf(z))*0.01f;
        int row = mt*16 + quad*4 + r;
        smem[row*HSTRIDE + col] = f2bf_fast(y);
      }
    }
  }
  // keep stage-2 accvgpr zero-inits below the epilogue's acc reads
  __builtin_amdgcn_sched_barrier(0);
  __syncthreads();

  // ---- stage 2: out = H@W2 + b2, M=32 K=256 N=144(->192 padded) ----
  // wave w owns n-tiles w*3..w*3+2. acc reuse: [2][3] of the same array.
#pragma unroll
  for (int mt=0; mt<2; mt++)
#pragma unroll
    for (int nt=0; nt<3; nt++) acc[mt][nt] = zero;

#pragma unroll
  for (int kt=0; kt<8; kt++){
    short8 a[2];
#pragma unroll
    for (int mt=0; mt<2; mt++)
      a[mt] = *reinterpret_cast<const short8*>(smem + (mt*16 + lm)*HSTRIDE + kt*32 + quad*8);
    short8 b[3];
#pragma unroll
    for (int nt=0; nt<3; nt++){
      int ntg = w*3 + nt;
      b[nt] = *reinterpret_cast<const short8*>(w2s + (size_t)((ntg*8 + kt)*64 + lane)*8);
    }
#pragma unroll
    for (int mt=0; mt<2; mt++)
#pragma unroll
      for (int nt=0; nt<3; nt++)
        acc[mt][nt] = __builtin_amdgcn_mfma_f32_16x16x32_bf16(a[mt], b[nt], acc[mt][nt], 0,0,0);
  }

  // plain cached stores (r1: nontemporal doubled WRITE_SIZE)
#pragma unroll
  for (int nt=0; nt<3; nt++){
    int j = (w*3 + nt)*16 + lm;
    if (j < 129){
      float bias = b2[j];
#pragma unroll
      for (int mt=0; mt<2; mt++){
#pragma unroll
        for (int r=0; r<4; r++){
          int row = mt*16 + quad*4 + r;
          out[(size_t)(blockIdx.x*32 + row)*129 + j] = acc[mt][nt][r] + bias;
        }
      }
    }
  }
}

extern "C" void kernel_launch(void* const* d_in, const int* in_sizes, int n_in,
                              void* d_out, int out_size, void* d_ws, size_t ws_size,
                              hipStream_t stream) {
  const float* xyz    = (const float*)d_in[0];
  const float* planes = (const float*)d_in[1];
  const float* lines  = (const float*)d_in[2];
  const float* W1     = (const float*)d_in[3];
  const float* b1     = (const float*)d_in[4];
  const float* W2     = (const float*)d_in[5];
  const float* b2     = (const float*)d_in[6];
  if (ws_size < (size_t)WS_NEEDED) return;   // workspace too small: fail loudly

  u16* pt  = (u16*)((char*)d_ws);
  u16* lt  = (u16*)((char*)d_ws + OFF_LINES_T);
  u16* w1s = (u16*)((char*)d_ws + OFF_W1S);
  u16* w2s = (u16*)((char*)d_ws + OFF_W2S);

  k_pre<<<NB_TP+NB_TL+NB_W1+NB_W2, 256, 0, stream>>>(planes, lines, W1, W2, pt, lt, w1s, w2s);
  k_main<<<16384, 256, 0, stream>>>(xyz, pt, lt, w1s, w2s, b1, b2, (float*)d_out);
}